// Round 8
// baseline (45.475 us; speedup 1.0000x reference)
//
#include <hip/hip_runtime.h>

// RBF activation: out[n,c,h,w] = sum_i w[c,i] * exp(-(x - mu_i)^2 / (2 sigma^2))
// x (8,64,256,256) f32, w (1,64,1,1,31) f32, mu (31,) f32, sigma scalar (== tap spacing).
//
// out = f_c(x): per-block LDS LUT (1024 x (value,delta) f32 pairs), linear interp.
// Hot path: ~6 VALU + ONE ds_read_b64 gather per element (measured best).
// LUT built IN-PLACE in the pair array (no scratch): LDS = 8328 B so all
// 16 blocks/CU stay co-resident (R4's 70% occupancy, the measured best).
// 4096 blocks, per-iter stride = one image -> thread channel constant.
// Interp error ~1.6e-5; window truncation ~3e-6 (threshold 1.77e-3).

static constexpr int KW    = 31;    // number of RBF taps
static constexpr int WIN   = 9;     // build window (radius 4)
static constexpr int RAD   = 4;
static constexpr int LUT_N = 1024;  // LUT intervals (1025 nodes)

typedef float f32x4 __attribute__((ext_vector_type(4)));
typedef float f32x2 __attribute__((ext_vector_type(2)));

// Windowed Gaussian-sum via geometric recurrence (LUT build path).
__device__ __forceinline__ float rbf_win(float xe, const float* __restrict__ wrow,
                                         float mu0, float inv_d, float cd2, float g) {
    const float t = (xe - mu0) * inv_d;             // position in tap units
    float jf = rintf(t) - (float)RAD;               // window start
    jf = fminf(fmaxf(jf, 0.0f), (float)(KW - WIN)); // clamp
    const int s = (int)jf;
    float n = t - jf;
    n = fminf(fmaxf(n, -32.0f), 40.0f);             // keep r0 finite far outside
    float E = __builtin_amdgcn_exp2f(cd2 * n * n);
    float r = __builtin_amdgcn_exp2f(cd2 * fmaf(-2.0f, n, 1.0f));
    float acc = 0.0f;
#pragma unroll
    for (int k = 0; k < WIN; ++k) {
        acc = fmaf(wrow[s + k], E, acc);
        E *= r;
        r *= g;
    }
    return acc;
}

// Build the (value, delta) pair LUT in place for block-uniform channel c.
// lutF = float view of lutP; node e value lives at lutF[2e] (= lutP[e].x),
// node 1024's value parks in lutF[2*1024] (spare slot), deltas fill lutF[2e+1].
__device__ __forceinline__ void lut_setup(const float* __restrict__ w,
                                          const float* __restrict__ mu,
                                          const float* __restrict__ sigma,
                                          int c, int tid,
                                          float* lutF, float* wrow,
                                          float& invh, float& nlo, float& tmax) {
    const float mu0   = mu[0];
    const float muL   = mu[KW - 1];
    const float dmu   = (muL - mu0) * (1.0f / (KW - 1));
    const float inv_d = 1.0f / dmu;
    const float sg    = sigma[0];
    const float cd2   = -1.4426950408889634f * dmu * dmu / (2.0f * sg * sg);
    const float g     = exp2f(2.0f * cd2);

    // LUT domain: [mu0 - pad, muL + pad], pad = 5.25 sigma (f there ~4e-8).
    const float pad  = 5.25f * sg;
    const float lo   = mu0 - pad;
    const float span = (muL - mu0) + 2.0f * pad;
    const float h    = span * (1.0f / (float)LUT_N);
    invh = (float)LUT_N / span;
    nlo  = -lo * invh;
    tmax = (float)LUT_N - 0.001f;

    if (tid < KW) wrow[tid] = w[c * KW + tid];
    __syncthreads();

    // Pass 1: 1025 node values into the .x slots (stride-2 writes).
    for (int e = tid; e <= LUT_N; e += 256)
        lutF[2 * e] = rbf_win(lo + (float)e * h, wrow, mu0, inv_d, cd2, g);
    __syncthreads();

    // Pass 2: deltas into the .y slots (stride-2 b32 reads: 2-way, free).
    for (int e = tid; e < LUT_N; e += 256)
        lutF[2 * e + 1] = lutF[2 * e + 2] - lutF[2 * e];
    __syncthreads();
}

__device__ __forceinline__ float lut_eval(float xe, const f32x2* __restrict__ lutP,
                                          float invh, float nlo, float tmax) {
    float t = fmaf(xe, invh, nlo);
    t = fminf(fmaxf(t, 0.0f), tmax);                 // v_med3
    const int j = (int)t;                            // trunc == floor (t >= 0)
    const float frac = t - (float)j;
    const f32x2 ab = lutP[j];                        // one ds_read_b64 gather
    return fmaf(frac, ab.y, ab.x);
}

// Specialized: N=8, C=64, HW=65536; 4096 blocks x 8 iterations.
// Per-iter stride 4096*256 = 1,048,576 f4 = one image -> channel constant.
__global__ __launch_bounds__(256) void rbf_lut_fixed(
    const float* __restrict__ x, const float* __restrict__ w,
    const float* __restrict__ mu, const float* __restrict__ sigma,
    float* __restrict__ out) {
    __shared__ float lutF[2 * LUT_N + 2];            // pairs + spare node slot
    __shared__ float wrow[32];
    const f32x2* lutP = reinterpret_cast<const f32x2*>(lutF);

    const int tid = threadIdx.x;
    const int gid = blockIdx.x * 256 + tid;
    const int c   = (gid >> 14) & 63;                // 16384 f4 per channel row

    // 2-deep prefetch issued before the LUT build hides HBM latency.
    int i4 = gid;
    f32x4 cur = reinterpret_cast<const f32x4*>(x)[i4];
    f32x4 nx1 = reinterpret_cast<const f32x4*>(x)[i4 + (1 << 20)];

    float invh, nlo, tmax;
    lut_setup(w, mu, sigma, c, tid, lutF, wrow, invh, nlo, tmax);

#pragma unroll
    for (int k = 0; k < 8; ++k) {
        f32x4 nx2;
        if (k < 6) nx2 = reinterpret_cast<const f32x4*>(x)[i4 + (2 << 20)];
        f32x4 ov;
        ov.x = lut_eval(cur.x, lutP, invh, nlo, tmax);
        ov.y = lut_eval(cur.y, lutP, invh, nlo, tmax);
        ov.z = lut_eval(cur.z, lutP, invh, nlo, tmax);
        ov.w = lut_eval(cur.w, lutP, invh, nlo, tmax);
        __builtin_nontemporal_store(ov, reinterpret_cast<f32x4*>(out) + i4);
        cur = nx1; nx1 = nx2;
        i4 += (1 << 20);                             // one image of float4s
    }
}

// Generic fallback for other shapes (assumes C=64 rows of 65536 via c_shift).
__global__ __launch_bounds__(256) void rbf_lut_generic(
    const float* __restrict__ x, const float* __restrict__ w,
    const float* __restrict__ mu, const float* __restrict__ sigma,
    float* __restrict__ out, int n4, int ntot, int iters, int c_shift) {
    __shared__ float lutF[2 * LUT_N + 2];
    __shared__ float wrow[32];
    const f32x2* lutP = reinterpret_cast<const f32x2*>(lutF);

    const int tid = threadIdx.x;
    const int gs  = gridDim.x * blockDim.x;
    const int gid = blockIdx.x * blockDim.x + tid;
    const int c   = (gid >> c_shift) & 63;

    float invh, nlo, tmax;
    lut_setup(w, mu, sigma, c, tid, lutF, wrow, invh, nlo, tmax);

    int i4 = gid;
    for (int k = 0; k < iters; ++k) {
        if (i4 < n4) {
            const f32x4 xv = reinterpret_cast<const f32x4*>(x)[i4];
            f32x4 ov;
            ov.x = lut_eval(xv.x, lutP, invh, nlo, tmax);
            ov.y = lut_eval(xv.y, lutP, invh, nlo, tmax);
            ov.z = lut_eval(xv.z, lutP, invh, nlo, tmax);
            ov.w = lut_eval(xv.w, lutP, invh, nlo, tmax);
            __builtin_nontemporal_store(ov, reinterpret_cast<f32x4*>(out) + i4);
        }
        i4 += gs;
    }

    // Scalar tail: exact 31-tap sum.
    const float mu0 = mu[0];
    const float dmu = (mu[KW - 1] - mu0) * (1.0f / (KW - 1));
    const float sg  = sigma[0];
    const float cd2x = -1.4426950408889634f / (2.0f * sg * sg);
    for (int i = n4 * 4 + gid; i < ntot; i += gs) {
        const float xe = x[i];
        const int ct = (i >> (c_shift + 2)) & 63;
        float acc = 0.0f;
        for (int qq = 0; qq < KW; ++qq) {
            const float d = xe - (mu0 + (float)qq * dmu);
            acc = fmaf(w[ct * KW + qq], __builtin_amdgcn_exp2f(cd2x * d * d), acc);
        }
        out[i] = acc;
    }
}

extern "C" void kernel_launch(void* const* d_in, const int* in_sizes, int n_in,
                              void* d_out, int out_size, void* d_ws, size_t ws_size,
                              hipStream_t stream) {
    const float* x  = (const float*)d_in[0];
    const float* w  = (const float*)d_in[1];
    const float* mu = (const float*)d_in[2];
    const float* sg = (const float*)d_in[3];
    float* out = (float*)d_out;

    if (out_size == 8 * 64 * 65536) {
        rbf_lut_fixed<<<4096, 256, 0, stream>>>(x, w, mu, sg, out);
    } else {
        const int n4     = out_size >> 2;
        const int blocks = 4096;
        const int gsz    = blocks * 256;
        const int iters  = (n4 + gsz - 1) / gsz;
        rbf_lut_generic<<<blocks, 256, 0, stream>>>(x, w, mu, sg, out, n4, out_size,
                                                    iters, 14);
    }
}